// Round 2
// baseline (669.855 us; speedup 1.0000x reference)
//
#include <hip/hip_runtime.h>
#include <hip/hip_bf16.h>
#include <math.h>

#define HID  128
#define FILT 128
#define NG   50
#define EPB  64   // edges per tile

typedef __attribute__((ext_vector_type(8))) short bf16x8;
typedef __attribute__((ext_vector_type(4))) float f32x4;
typedef __attribute__((ext_vector_type(4))) int   i32x4;
typedef unsigned short u16;

__device__ __forceinline__ u16 f2bf(float f) {
    __hip_bfloat16 h = __float2bfloat16(f);
    return *reinterpret_cast<u16*>(&h);
}
__device__ __forceinline__ float bf2f(u16 v) {
    union { unsigned u; float f; } x; x.u = ((unsigned)v) << 16; return x.f;
}

__device__ __forceinline__ float sspf(float v) {
    float sp = (v > 15.f) ? v : log1pf(__expf(v));
    return sp - 0.69314718056f;
}

// ---------------------------------------------------------------------------
// prep: transpose + bf16-convert edge-MLP weights.
// ---------------------------------------------------------------------------
__global__ void prep_w(const float* __restrict__ w1, const float* __restrict__ w2,
                       u16* __restrict__ w1T, u16* __restrict__ w2T)
{
    int t = blockIdx.x * 256 + threadIdx.x;
    if (t < 128 * 64) {
        int n = t >> 6, k = t & 63;
        w1T[t] = (k < NG) ? f2bf(w1[k * FILT + n]) : (u16)0;
    }
    if (t < 128 * 128) {
        int n = t >> 7, k = t & 127;
        w2T[t] = f2bf(w2[k * FILT + n]);
    }
}

// ---------------------------------------------------------------------------
// counting-sort of edges by destination row
// ---------------------------------------------------------------------------
__global__ void hist_kernel(const int* __restrict__ eidx, int* __restrict__ cnt, int E)
{
    for (int e = blockIdx.x * 256 + threadIdx.x; e < E; e += gridDim.x * 256)
        atomicAdd(&cnt[eidx[e]], 1);
}

#define SCAN_CHUNK 1024
__global__ void scan_part(const int* __restrict__ cnt, int* __restrict__ part, int N)
{
    __shared__ int red[256];
    int b = blockIdx.x, tid = threadIdx.x;
    int base = b * SCAN_CHUNK + tid * 4;
    int s = 0;
#pragma unroll
    for (int i = 0; i < 4; ++i) { int idx = base + i; if (idx < N) s += cnt[idx]; }
    red[tid] = s;
    __syncthreads();
    for (int off = 128; off > 0; off >>= 1) {
        if (tid < off) red[tid] += red[tid + off];
        __syncthreads();
    }
    if (tid == 0) part[b] = red[0];
}

__global__ void scan_write(const int* __restrict__ cnt, const int* __restrict__ part,
                           int* __restrict__ cur, int N, int nblk)
{
    __shared__ int sc[256];
    int b = blockIdx.x, tid = threadIdx.x;
    // base = sum of partials before this block (each thread computes redundantly)
    int base = 0;
    for (int i = 0; i < b; ++i) base += part[i];
    // thread-local 4-element scan
    int gbase = b * SCAN_CHUNK + tid * 4;
    int v[4];
#pragma unroll
    for (int i = 0; i < 4; ++i) { int idx = gbase + i; v[i] = (idx < N) ? cnt[idx] : 0; }
    int tsum = v[0] + v[1] + v[2] + v[3];
    sc[tid] = tsum;
    __syncthreads();
    // Hillis-Steele inclusive scan over 256 thread sums
    for (int off = 1; off < 256; off <<= 1) {
        int add = (tid >= off) ? sc[tid - off] : 0;
        __syncthreads();
        sc[tid] += add;
        __syncthreads();
    }
    int tpre = base + sc[tid] - tsum;   // exclusive prefix for this thread
    int run = 0;
#pragma unroll
    for (int i = 0; i < 4; ++i) {
        int idx = gbase + i;
        if (idx < N) cur[idx] = tpre + run;
        run += v[i];
    }
}

__global__ void scatter_perm(const int* __restrict__ eidx, int* __restrict__ cur,
                             int* __restrict__ perm, int E)
{
    for (int e = blockIdx.x * 256 + threadIdx.x; e < E; e += gridDim.x * 256) {
        int r = eidx[e];
        int p = atomicAdd(&cur[r], 1);
        perm[p] = e;
    }
}

// ---------------------------------------------------------------------------
// fp32 node GEMM: C[r][c] = act( sum_k A[r][k]*Wg[k][c] + bias[c] )
// ---------------------------------------------------------------------------
template<int ACT>
__global__ __launch_bounds__(256) void node_gemm(
    const float* __restrict__ A, const float* __restrict__ Wg,
    const float* __restrict__ bias, float* __restrict__ C, int nrows)
{
    __shared__ float sA[32][128];
    const int tid = threadIdx.x;
    const int tx = tid & 31;
    const int ty = tid >> 5;
    const int r0 = blockIdx.x * 32;

    for (int i = tid; i < 32 * 128; i += 256) {
        int r = i >> 7, k = i & 127;
        sA[r][k] = (r0 + r < nrows) ? A[(r0 + r) * HID + k] : 0.f;
    }
    __syncthreads();

    f32x4 acc[4];
#pragma unroll
    for (int i = 0; i < 4; ++i) acc[i] = (f32x4){0.f, 0.f, 0.f, 0.f};

#pragma unroll 4
    for (int k = 0; k < 128; ++k) {
        f32x4 wv = *reinterpret_cast<const f32x4*>(Wg + k * FILT + tx * 4);
        float a0 = sA[ty * 4 + 0][k];
        float a1 = sA[ty * 4 + 1][k];
        float a2 = sA[ty * 4 + 2][k];
        float a3 = sA[ty * 4 + 3][k];
        acc[0] += a0 * wv; acc[1] += a1 * wv; acc[2] += a2 * wv; acc[3] += a3 * wv;
    }

    f32x4 bv = (f32x4){0.f, 0.f, 0.f, 0.f};
    if (bias) bv = *reinterpret_cast<const f32x4*>(bias + tx * 4);
#pragma unroll
    for (int i = 0; i < 4; ++i) {
        int row = r0 + ty * 4 + i;
        if (row < nrows) {
            f32x4 o = acc[i] + bv;
            if (ACT) { o[0] = sspf(o[0]); o[1] = sspf(o[1]); o[2] = sspf(o[2]); o[3] = sspf(o[3]); }
            *reinterpret_cast<f32x4*>(C + row * FILT + tx * 4) = o;
        }
    }
}

// ---------------------------------------------------------------------------
// fused edge kernel over ROW-SORTED edges:
// distances -> gaussians -> MLP (bf16 MFMA) -> cutoff -> W to LDS ->
// segmented gather-modulate-sum with ~1 atomic flush per row-run.
// ---------------------------------------------------------------------------
__global__ __launch_bounds__(256, 3) void edge_kernel(
    const float* __restrict__ pos,
    const int*   __restrict__ eidx,   // [2*E]
    const int*   __restrict__ perm,   // [E] edge ids sorted by row
    const u16*   __restrict__ w1T,    // [128][64] bf16
    const u16*   __restrict__ w2T,    // [128][128] bf16
    const float* __restrict__ b1,
    const float* __restrict__ b2,
    const float* __restrict__ x,      // [N][128] f32
    float*       __restrict__ agg,    // [N][128] f32 (pre-zeroed)
    int E)
{
    __shared__ u16  sw2[FILT * FILT];   // [n][k] bf16, XOR-swizzled
    __shared__ u16  sU[EPB * FILT];     // union: gaussians / t1 / W tiles
    __shared__ float sC[EPB];
    __shared__ float sd[EPB];
    __shared__ int   srow[EPB];
    __shared__ int   scol[EPB];
    __shared__ float sb1[FILT];
    __shared__ float sb2[FILT];

    const int tid  = threadIdx.x;
    const int lane = tid & 63;
    const int wv   = tid >> 6;
    const int l15  = lane & 15;
    const int l4   = lane >> 4;

    // stage swizzled w2 once per persistent block
    for (int c = tid; c < FILT * 16; c += 256) {
        int n = c >> 4, kb = c & 15;
        i32x4 v = *reinterpret_cast<const i32x4*>(w2T + n * FILT + kb * 8);
        int byteoff = n * 256 + ((kb * 16) ^ ((n & 7) << 4));
        *reinterpret_cast<i32x4*>(reinterpret_cast<char*>(sw2) + byteoff) = v;
    }
    if (tid < FILT) { sb1[tid] = b1[tid]; sb2[tid] = b2[tid]; }

    // w1 fragments are loop-invariant: hoist to registers
    bf16x8 bw1[2][2];
#pragma unroll
    for (int nt = 0; nt < 2; ++nt)
#pragma unroll
        for (int s = 0; s < 2; ++s) {
            int n = wv * 32 + nt * 16 + l15;
            bw1[nt][s] = *reinterpret_cast<const bf16x8*>(w1T + n * 64 + s * 32 + l4 * 8);
        }
    __syncthreads();

    const float GSTEP = 10.0f / 49.0f;
    const float COEFF = -0.5f / (GSTEP * GSTEP);
    const int ntiles = (E + EPB - 1) / EPB;

    for (int tile = blockIdx.x; tile < ntiles; tile += gridDim.x) {
        const int e0 = tile * EPB;

        // --- phase 1: per-edge scalars (sorted order) -----------------------
        if (tid < EPB) {
            int es = e0 + tid;
            int r = 0, c = 0; float d = 0.f, Cf = 0.f;
            if (es < E) {
                int p = perm[es];
                r = eidx[p]; c = eidx[E + p];
                float dx = pos[3 * r + 0] - pos[3 * c + 0];
                float dy = pos[3 * r + 1] - pos[3 * c + 1];
                float dz = pos[3 * r + 2] - pos[3 * c + 2];
                d  = sqrtf(dx * dx + dy * dy + dz * dz);
                Cf = 0.5f * (cosf(d * 0.3141592653589793f) + 1.0f);
            }
            srow[tid] = r; scol[tid] = c; sd[tid] = d; sC[tid] = Cf;
        }
        __syncthreads();

        // --- phase 2: gaussian tile [64 e][64 g] bf16, swizzled -------------
        for (int i = tid; i < EPB * 64; i += 256) {
            int e = i >> 6, g = i & 63;
            float v = 0.f;
            if (g < NG) { float t = sd[e] - (float)g * GSTEP; v = __expf(COEFF * t * t); }
            int byteoff = e * 128 + ((g * 2) ^ ((e & 7) << 4));
            *reinterpret_cast<u16*>(reinterpret_cast<char*>(sU) + byteoff) = f2bf(v);
        }
        __syncthreads();

        // --- GEMM1: t1 = ssp(gauss @ w1 + b1), K=64 -------------------------
        f32x4 acc1[4][2];
#pragma unroll
        for (int mt = 0; mt < 4; ++mt)
#pragma unroll
            for (int nt = 0; nt < 2; ++nt) acc1[mt][nt] = (f32x4){0.f, 0.f, 0.f, 0.f};

#pragma unroll
        for (int mt = 0; mt < 4; ++mt) {
#pragma unroll
            for (int s = 0; s < 2; ++s) {
                int e = mt * 16 + l15;
                int byteoff = e * 128 + (((s * 64 + l4 * 16)) ^ ((e & 7) << 4));
                bf16x8 af = *reinterpret_cast<const bf16x8*>(reinterpret_cast<char*>(sU) + byteoff);
                acc1[mt][0] = __builtin_amdgcn_mfma_f32_16x16x32_bf16(af, bw1[0][s], acc1[mt][0], 0, 0, 0);
                acc1[mt][1] = __builtin_amdgcn_mfma_f32_16x16x32_bf16(af, bw1[1][s], acc1[mt][1], 0, 0, 0);
            }
        }
        __syncthreads();

        // ssp + write t1 tile [64 e][128 k] bf16, swizzled
#pragma unroll
        for (int mt = 0; mt < 4; ++mt)
#pragma unroll
            for (int nt = 0; nt < 2; ++nt)
#pragma unroll
                for (int r = 0; r < 4; ++r) {
                    int m = mt * 16 + l4 * 4 + r;
                    int n = wv * 32 + nt * 16 + l15;
                    float v = sspf(acc1[mt][nt][r] + sb1[n]);
                    int byteoff = m * 256 + ((n * 2) ^ ((m & 7) << 4));
                    *reinterpret_cast<u16*>(reinterpret_cast<char*>(sU) + byteoff) = f2bf(v);
                }
        __syncthreads();

        // --- GEMM2: W = t1 @ w2 + b2, K=128 ---------------------------------
        f32x4 acc2[4][2];
#pragma unroll
        for (int mt = 0; mt < 4; ++mt)
#pragma unroll
            for (int nt = 0; nt < 2; ++nt) acc2[mt][nt] = (f32x4){0.f, 0.f, 0.f, 0.f};

#pragma unroll
        for (int s = 0; s < 4; ++s) {
            bf16x8 bw2[2];
#pragma unroll
            for (int nt = 0; nt < 2; ++nt) {
                int n = wv * 32 + nt * 16 + l15;
                int byteoff = n * 256 + (((s * 64 + l4 * 16)) ^ ((n & 7) << 4));
                bw2[nt] = *reinterpret_cast<const bf16x8*>(reinterpret_cast<char*>(sw2) + byteoff);
            }
#pragma unroll
            for (int mt = 0; mt < 4; ++mt) {
                int e = mt * 16 + l15;
                int byteoff = e * 256 + (((s * 64 + l4 * 16)) ^ ((e & 7) << 4));
                bf16x8 af = *reinterpret_cast<const bf16x8*>(reinterpret_cast<char*>(sU) + byteoff);
                acc2[mt][0] = __builtin_amdgcn_mfma_f32_16x16x32_bf16(af, bw2[0], acc2[mt][0], 0, 0, 0);
                acc2[mt][1] = __builtin_amdgcn_mfma_f32_16x16x32_bf16(af, bw2[1], acc2[mt][1], 0, 0, 0);
            }
        }

        // --- store W (x cutoff) to LDS as bf16, swizzled --------------------
#pragma unroll
        for (int mt = 0; mt < 4; ++mt)
#pragma unroll
            for (int nt = 0; nt < 2; ++nt) {
                int n = wv * 32 + nt * 16 + l15;
                float bb = sb2[n];
#pragma unroll
                for (int r = 0; r < 4; ++r) {
                    int el = mt * 16 + l4 * 4 + r;
                    float Wv = (acc2[mt][nt][r] + bb) * sC[el];
                    int byteoff = el * 256 + ((n * 2) ^ ((el & 7) << 4));
                    *reinterpret_cast<u16*>(reinterpret_cast<char*>(sU) + byteoff) = f2bf(Wv);
                }
            }
        __syncthreads();

        // --- segmented gather-modulate-sum ----------------------------------
        // thread -> (column c, edge half): serial walk over 32 sorted edges,
        // flush one atomicAdd per row-run.
        {
            const int c    = tid & 127;
            const int half = tid >> 7;
            const int eb   = half * 32;

            // preload x-gather values into registers (independent loads)
            float xv[32];
#pragma unroll
            for (int i = 0; i < 32; ++i)
                xv[i] = x[(size_t)scol[eb + i] * HID + c];

            float acc = 0.f;
            int rcur = srow[eb];
#pragma unroll
            for (int i = 0; i < 32; ++i) {
                int e = eb + i;
                int r = srow[e];
                if (r != rcur) {
                    atomicAdd(agg + (size_t)rcur * HID + c, acc);
                    acc = 0.f; rcur = r;
                }
                int bo = e * 256 + ((c * 2) ^ ((e & 7) << 4));
                float Wv = bf2f(*reinterpret_cast<u16*>(reinterpret_cast<char*>(sU) + bo));
                acc = fmaf(Wv, xv[i], acc);
            }
            atomicAdd(agg + (size_t)rcur * HID + c, acc);
        }
        __syncthreads();
    }
}

// ---------------------------------------------------------------------------
extern "C" void kernel_launch(void* const* d_in, const int* in_sizes, int n_in,
                              void* d_out, int out_size, void* d_ws, size_t ws_size,
                              hipStream_t stream)
{
    const float* h    = (const float*)d_in[0];
    const float* pos  = (const float*)d_in[1];
    const int*   eidx = (const int*)  d_in[2];
    const float* w1   = (const float*)d_in[3];
    const float* b1   = (const float*)d_in[4];
    const float* w2   = (const float*)d_in[5];
    const float* b2   = (const float*)d_in[6];
    const float* lin1 = (const float*)d_in[7];
    const float* lin2 = (const float*)d_in[8];
    const float* l2b  = (const float*)d_in[9];
    const float* linw = (const float*)d_in[10];
    const float* linb = (const float*)d_in[11];

    const int N = in_sizes[0] / HID;
    const int E = in_sizes[2] / 2;

    char* ws = (char*)d_ws;
    size_t off = 0;
    auto alloc = [&](size_t bytes) { char* p = ws + off; off = (off + bytes + 255) & ~(size_t)255; return p; };

    float* xbuf = (float*)alloc((size_t)N * HID * sizeof(float));
    u16*   w1T  = (u16*)  alloc(128 * 64 * sizeof(u16));
    u16*   w2T  = (u16*)  alloc(128 * 128 * sizeof(u16));
    int*   cnt  = (int*)  alloc((size_t)N * sizeof(int));
    int*   cur  = (int*)  alloc((size_t)N * sizeof(int));
    int*   part = (int*)  alloc(256 * sizeof(int));
    int*   perm = (int*)  alloc((size_t)E * sizeof(int));

    float* agg = (float*)d_out;

    hipMemsetAsync(d_out, 0, (size_t)out_size * sizeof(float), stream);
    hipMemsetAsync(cnt, 0, (size_t)N * sizeof(int), stream);

    prep_w<<<64, 256, 0, stream>>>(w1, w2, w1T, w2T);

    // counting sort of edges by destination row
    hist_kernel<<<1024, 256, 0, stream>>>(eidx, cnt, E);
    const int nblk = (N + SCAN_CHUNK - 1) / SCAN_CHUNK;
    scan_part<<<nblk, 256, 0, stream>>>(cnt, part, N);
    scan_write<<<nblk, 256, 0, stream>>>(cnt, part, cur, N, nblk);
    scatter_perm<<<1024, 256, 0, stream>>>(eidx, cur, perm, E);

    // x = h @ lin1
    node_gemm<0><<<(N + 31) / 32, 256, 0, stream>>>(h, lin1, nullptr, xbuf, N);

    // fused edge pipeline + segmented scatter into agg (= d_out)
    edge_kernel<<<768, 256, 0, stream>>>(pos, eidx, perm, w1T, w2T, b1, b2, xbuf, agg, E);

    // tmp = ssp(agg @ lin2 + l2b)
    node_gemm<1><<<(N + 31) / 32, 256, 0, stream>>>(agg, lin2, l2b, xbuf, N);

    // out = tmp @ lin_w + lin_b
    node_gemm<0><<<(N + 31) / 32, 256, 0, stream>>>(xbuf, linw, linb, (float*)d_out, N);
}

// Round 3
// 387.488 us; speedup vs baseline: 1.7287x; 1.7287x over previous
//
#include <hip/hip_runtime.h>
#include <hip/hip_bf16.h>
#include <math.h>

#define HID   128
#define NG    50
#define TN    4096          // table entries
#define TMAXD 16.0f         // table covers d in [0, 16)
#define RPB   16            // rows per block in CSR kernel

typedef __attribute__((ext_vector_type(4))) float f32x4;

#define LOG2F 0.69314718056f

__device__ __forceinline__ float sspf(float v) {
    // shifted softplus via hw v_exp/v_log (log1pf libm was a VALU hog)
    if (v > 15.f) return v - LOG2F;
    return __logf(1.f + __expf(v)) - LOG2F;
}

// ---------------------------------------------------------------------------
// Build Wc table: T[s][c] = ( ssp(gauss(d_s)@w1 + b1) @ w2 + b2 )[c] * C(d_s)
// d_s = s * (TMAXD/TN). All f32 — exact MLP at sample points.
// ---------------------------------------------------------------------------
__global__ __launch_bounds__(256) void table_kernel(
    const float* __restrict__ w1, const float* __restrict__ b1,
    const float* __restrict__ w2, const float* __restrict__ b2,
    float* __restrict__ T)
{
    __shared__ float sattr[64][64];   // [sample][gauss], padded
    __shared__ float st1[64][128];

    const int tid = threadIdx.x;
    const int s0 = blockIdx.x * 64;
    const float TSTEP = TMAXD / TN;
    const float GSTEP = 10.0f / 49.0f;
    const float COEFF = -0.5f / (GSTEP * GSTEP);

    // phase A: gaussians
    for (int idx = tid; idx < 64 * 64; idx += 256) {
        int s = idx >> 6, g = idx & 63;
        float v = 0.f;
        if (g < NG) {
            float d = (float)(s0 + s) * TSTEP;
            float t = d - (float)g * GSTEP;
            v = __expf(COEFF * t * t);
        }
        sattr[s][g] = v;
    }
    __syncthreads();

    // phase B: t1 = ssp(attr @ w1 + b1)
    {
        const int f = tid & 127;
        const int sh = tid >> 7;
        for (int j = 0; j < 32; ++j) {
            int s = sh * 32 + j;
            float acc = b1[f];
#pragma unroll
            for (int g = 0; g < NG; ++g)
                acc = fmaf(sattr[s][g], w1[g * 128 + f], acc);
            st1[s][f] = sspf(acc);
        }
    }
    __syncthreads();

    // phase C: W = (t1 @ w2 + b2) * C(d)
    {
        const int c = tid & 127;
        const int sh = tid >> 7;
        for (int j = 0; j < 32; ++j) {
            int s = sh * 32 + j;
            float acc = b2[c];
#pragma unroll 8
            for (int f = 0; f < 128; ++f)
                acc = fmaf(st1[s][f], w2[f * 128 + c], acc);
            float d = (float)(s0 + s) * TSTEP;
            float Cf = 0.5f * (__cosf(d * 0.31415926535f) + 1.0f);
            T[(size_t)(s0 + s) * 128 + c] = acc * Cf;
        }
    }
}

// ---------------------------------------------------------------------------
// counting sort by destination row
// ---------------------------------------------------------------------------
__global__ void hist_kernel(const int* __restrict__ eidx, int* __restrict__ cnt, int E)
{
    for (int e = blockIdx.x * 256 + threadIdx.x; e < E; e += gridDim.x * 256)
        atomicAdd(&cnt[eidx[e]], 1);
}

#define SCAN_CHUNK 1024
__global__ void scan_part(const int* __restrict__ cnt, int* __restrict__ part, int N)
{
    __shared__ int red[256];
    int b = blockIdx.x, tid = threadIdx.x;
    int base = b * SCAN_CHUNK + tid * 4;
    int s = 0;
#pragma unroll
    for (int i = 0; i < 4; ++i) { int idx = base + i; if (idx < N) s += cnt[idx]; }
    red[tid] = s;
    __syncthreads();
    for (int off = 128; off > 0; off >>= 1) {
        if (tid < off) red[tid] += red[tid + off];
        __syncthreads();
    }
    if (tid == 0) part[b] = red[0];
}

__global__ void scan_write(const int* __restrict__ cnt, const int* __restrict__ part,
                           int* __restrict__ cur, int N, int nblk)
{
    __shared__ int sc[256];
    int b = blockIdx.x, tid = threadIdx.x;
    int base = 0;
    for (int i = 0; i < b; ++i) base += part[i];
    int gbase = b * SCAN_CHUNK + tid * 4;
    int v[4];
#pragma unroll
    for (int i = 0; i < 4; ++i) { int idx = gbase + i; v[i] = (idx < N) ? cnt[idx] : 0; }
    int tsum = v[0] + v[1] + v[2] + v[3];
    sc[tid] = tsum;
    __syncthreads();
    for (int off = 1; off < 256; off <<= 1) {
        int add = (tid >= off) ? sc[tid - off] : 0;
        __syncthreads();
        sc[tid] += add;
        __syncthreads();
    }
    int tpre = base + sc[tid] - tsum;
    int run = 0;
#pragma unroll
    for (int i = 0; i < 4; ++i) {
        int idx = gbase + i;
        if (idx < N) cur[idx] = tpre + run;
        run += v[i];
    }
}

// scatter into sorted order; also compute per-edge table coordinate t = d*scale
__global__ void scatter2(const int* __restrict__ eidx, const float* __restrict__ pos,
                         int* __restrict__ cur, float* __restrict__ tS,
                         int* __restrict__ colS, int E)
{
    for (int e = blockIdx.x * 256 + threadIdx.x; e < E; e += gridDim.x * 256) {
        int r = eidx[e], c = eidx[E + e];
        float dx = pos[3 * r + 0] - pos[3 * c + 0];
        float dy = pos[3 * r + 1] - pos[3 * c + 1];
        float dz = pos[3 * r + 2] - pos[3 * c + 2];
        float d = sqrtf(dx * dx + dy * dy + dz * dz);
        int p = atomicAdd(&cur[r], 1);
        tS[p] = d * (TN / TMAXD);
        colS[p] = c;
    }
}

// ---------------------------------------------------------------------------
// fp32 node GEMM: C[r][c] = act( sum_k A[r][k]*Wg[k][c] + bias[c] )
// ---------------------------------------------------------------------------
template<int ACT>
__global__ __launch_bounds__(256) void node_gemm(
    const float* __restrict__ A, const float* __restrict__ Wg,
    const float* __restrict__ bias, float* __restrict__ C, int nrows)
{
    __shared__ float sA[32][128];
    const int tid = threadIdx.x;
    const int tx = tid & 31;
    const int ty = tid >> 5;
    const int r0 = blockIdx.x * 32;

    for (int i = tid; i < 32 * 128; i += 256) {
        int r = i >> 7, k = i & 127;
        sA[r][k] = (r0 + r < nrows) ? A[(size_t)(r0 + r) * HID + k] : 0.f;
    }
    __syncthreads();

    f32x4 acc[4];
#pragma unroll
    for (int i = 0; i < 4; ++i) acc[i] = (f32x4){0.f, 0.f, 0.f, 0.f};

#pragma unroll 4
    for (int k = 0; k < 128; ++k) {
        f32x4 wv = *reinterpret_cast<const f32x4*>(Wg + k * HID + tx * 4);
        float a0 = sA[ty * 4 + 0][k];
        float a1 = sA[ty * 4 + 1][k];
        float a2 = sA[ty * 4 + 2][k];
        float a3 = sA[ty * 4 + 3][k];
        acc[0] += a0 * wv; acc[1] += a1 * wv; acc[2] += a2 * wv; acc[3] += a3 * wv;
    }

    f32x4 bv = (f32x4){0.f, 0.f, 0.f, 0.f};
    if (bias) bv = *reinterpret_cast<const f32x4*>(bias + tx * 4);
#pragma unroll
    for (int i = 0; i < 4; ++i) {
        int row = r0 + ty * 4 + i;
        if (row < nrows) {
            f32x4 o = acc[i] + bv;
            if (ACT) { o[0] = sspf(o[0]); o[1] = sspf(o[1]); o[2] = sspf(o[2]); o[3] = sspf(o[3]); }
            *reinterpret_cast<f32x4*>(C + (size_t)row * HID + tx * 4) = o;
        }
    }
}

// ---------------------------------------------------------------------------
// CSR message passing with table lerp:
//   agg[r][c] = sum_{e in row r} lerp(T, t_e)[c] * x[col_e][c]
// block owns RPB rows; thread = (column, row-parity); plain stores, no atomics.
// ---------------------------------------------------------------------------
__global__ __launch_bounds__(256) void edge_csr(
    const int*   __restrict__ rowend,   // cur after scatter = CSR end offsets
    const float* __restrict__ tS,
    const int*   __restrict__ colS,
    const float* __restrict__ T,        // [TN][128]
    const float* __restrict__ x,        // [N][128]
    float*       __restrict__ agg,      // [N][128]
    int N)
{
    const int c    = threadIdx.x & 127;
    const int slot = threadIdx.x >> 7;
    const int r0   = blockIdx.x * RPB;
    const int rend = min(r0 + RPB, N);

    for (int r = r0 + slot; r < rend; r += 2) {
        int e = (r == 0) ? 0 : rowend[r - 1];
        const int ee = rowend[r];
        float acc = 0.f;

        for (; e + 3 < ee; e += 4) {
            float t0 = tS[e], t1 = tS[e + 1], t2 = tS[e + 2], t3 = tS[e + 3];
            int   c0 = colS[e], c1 = colS[e + 1], c2 = colS[e + 2], c3 = colS[e + 3];
            int i0 = min((int)t0, TN - 2), i1 = min((int)t1, TN - 2);
            int i2 = min((int)t2, TN - 2), i3 = min((int)t3, TN - 2);
            float f0 = t0 - (float)i0, f1 = t1 - (float)i1;
            float f2 = t2 - (float)i2, f3 = t3 - (float)i3;
            const float* p0 = T + (size_t)i0 * HID + c;
            const float* p1 = T + (size_t)i1 * HID + c;
            const float* p2 = T + (size_t)i2 * HID + c;
            const float* p3 = T + (size_t)i3 * HID + c;
            float wa0 = p0[0], wb0 = p0[HID];
            float wa1 = p1[0], wb1 = p1[HID];
            float wa2 = p2[0], wb2 = p2[HID];
            float wa3 = p3[0], wb3 = p3[HID];
            float xv0 = x[(size_t)c0 * HID + c];
            float xv1 = x[(size_t)c1 * HID + c];
            float xv2 = x[(size_t)c2 * HID + c];
            float xv3 = x[(size_t)c3 * HID + c];
            acc = fmaf(fmaf(f0, wb0 - wa0, wa0), xv0, acc);
            acc = fmaf(fmaf(f1, wb1 - wa1, wa1), xv1, acc);
            acc = fmaf(fmaf(f2, wb2 - wa2, wa2), xv2, acc);
            acc = fmaf(fmaf(f3, wb3 - wa3, wa3), xv3, acc);
        }
        for (; e < ee; ++e) {
            float t0 = tS[e];
            int   c0 = colS[e];
            int   i0 = min((int)t0, TN - 2);
            float f0 = t0 - (float)i0;
            const float* p0 = T + (size_t)i0 * HID + c;
            float W0 = fmaf(f0, p0[HID] - p0[0], p0[0]);
            acc = fmaf(W0, x[(size_t)c0 * HID + c], acc);
        }
        agg[(size_t)r * HID + c] = acc;
    }
}

// ---------------------------------------------------------------------------
extern "C" void kernel_launch(void* const* d_in, const int* in_sizes, int n_in,
                              void* d_out, int out_size, void* d_ws, size_t ws_size,
                              hipStream_t stream)
{
    const float* h    = (const float*)d_in[0];
    const float* pos  = (const float*)d_in[1];
    const int*   eidx = (const int*)  d_in[2];
    const float* w1   = (const float*)d_in[3];
    const float* b1   = (const float*)d_in[4];
    const float* w2   = (const float*)d_in[5];
    const float* b2   = (const float*)d_in[6];
    const float* lin1 = (const float*)d_in[7];
    const float* lin2 = (const float*)d_in[8];
    const float* l2b  = (const float*)d_in[9];
    const float* linw = (const float*)d_in[10];
    const float* linb = (const float*)d_in[11];

    const int N = in_sizes[0] / HID;
    const int E = in_sizes[2] / 2;

    char* ws = (char*)d_ws;
    size_t off = 0;
    auto alloc = [&](size_t bytes) { char* p = ws + off; off = (off + bytes + 255) & ~(size_t)255; return p; };

    float* xbuf = (float*)alloc((size_t)N * HID * sizeof(float));  // x, then tmp
    float* T    = (float*)alloc((size_t)TN * HID * sizeof(float));
    int*   cnt  = (int*)  alloc((size_t)N * sizeof(int));
    int*   cur  = (int*)  alloc((size_t)N * sizeof(int));
    int*   part = (int*)  alloc(256 * sizeof(int));
    float* tS   = (float*)alloc((size_t)E * sizeof(float));
    int*   colS = (int*)  alloc((size_t)E * sizeof(int));

    float* agg = (float*)d_out;   // edge_csr writes every element; no memset needed

    hipMemsetAsync(cnt, 0, (size_t)N * sizeof(int), stream);

    // Wc(d) lookup table (f32, exact MLP at 4096 sample distances)
    table_kernel<<<TN / 64, 256, 0, stream>>>(w1, b1, w2, b2, T);

    // counting sort of edges by destination row (cur -> CSR end offsets)
    hist_kernel<<<2048, 256, 0, stream>>>(eidx, cnt, E);
    const int nblk = (N + SCAN_CHUNK - 1) / SCAN_CHUNK;
    scan_part<<<nblk, 256, 0, stream>>>(cnt, part, N);
    scan_write<<<nblk, 256, 0, stream>>>(cnt, part, cur, N, nblk);
    scatter2<<<2048, 256, 0, stream>>>(eidx, pos, cur, tS, colS, E);

    // x = h @ lin1
    node_gemm<0><<<(N + 31) / 32, 256, 0, stream>>>(h, lin1, nullptr, xbuf, N);

    // CSR gather-modulate-sum into agg (= d_out), no atomics
    edge_csr<<<(N + RPB - 1) / RPB, 256, 0, stream>>>(cur, tS, colS, T, xbuf, agg, N);

    // tmp = ssp(agg @ lin2 + l2b)   (xbuf reused; x dead)
    node_gemm<1><<<(N + 31) / 32, 256, 0, stream>>>(agg, lin2, l2b, xbuf, N);

    // out = tmp @ lin_w + lin_b
    node_gemm<0><<<(N + 31) / 32, 256, 0, stream>>>(xbuf, linw, linb, (float*)d_out, N);
}

// Round 4
// 310.921 us; speedup vs baseline: 2.1544x; 1.2463x over previous
//
#include <hip/hip_runtime.h>
#include <hip/hip_bf16.h>
#include <math.h>

#define HID   128
#define NG    50
#define TN    4096          // table entries
#define TMAXD 16.0f         // table covers d in [0, 16)
#define RPB   16            // rows per block in CSR kernel
#define TSPB  16            // samples per block in table kernel

typedef __attribute__((ext_vector_type(4))) float f32x4;
typedef unsigned short u16;

#define LOG2F 0.69314718056f

__device__ __forceinline__ float sspf(float v) {
    if (v > 15.f) return v - LOG2F;
    return __logf(1.f + __expf(v)) - LOG2F;
}

__device__ __forceinline__ u16 f2bf(float f) {
    __hip_bfloat16 h = __float2bfloat16(f);
    return *reinterpret_cast<u16*>(&h);
}
__device__ __forceinline__ float bf2f(u16 v) {
    union { unsigned u; float f; } x; x.u = ((unsigned)v) << 16; return x.f;
}

// ---------------------------------------------------------------------------
// Build Wc table: T[s][c] = ( ssp(gauss(d_s)@w1 + b1) @ w2 + b2 )[c] * C(d_s)
// 256 blocks x 16 samples — full-GPU parallel.
// ---------------------------------------------------------------------------
__global__ __launch_bounds__(256) void table_kernel(
    const float* __restrict__ w1, const float* __restrict__ b1,
    const float* __restrict__ w2, const float* __restrict__ b2,
    float* __restrict__ T)
{
    __shared__ float sattr[TSPB][64];
    __shared__ float st1[TSPB][128];

    const int tid = threadIdx.x;
    const int s0 = blockIdx.x * TSPB;
    const float TSTEP = TMAXD / TN;
    const float GSTEP = 10.0f / 49.0f;
    const float COEFF = -0.5f / (GSTEP * GSTEP);

    // phase A: gaussians [16][50]
    for (int idx = tid; idx < TSPB * 64; idx += 256) {
        int s = idx >> 6, g = idx & 63;
        float v = 0.f;
        if (g < NG) {
            float d = (float)(s0 + s) * TSTEP;
            float t = d - (float)g * GSTEP;
            v = __expf(COEFF * t * t);
        }
        sattr[s][g] = v;
    }
    __syncthreads();

    const int c  = tid & 127;
    const int sh = tid >> 7;

    // phase B: t1 = ssp(attr @ w1 + b1)   (w1 reads L2-broadcast across blocks)
    for (int s = sh; s < TSPB; s += 2) {
        float acc = b1[c];
#pragma unroll
        for (int g = 0; g < NG; ++g)
            acc = fmaf(sattr[s][g], w1[g * 128 + c], acc);
        st1[s][c] = sspf(acc);
    }
    __syncthreads();

    // phase C: W = (t1 @ w2 + b2) * C(d)
    for (int s = sh; s < TSPB; s += 2) {
        float acc = b2[c];
#pragma unroll 8
        for (int k = 0; k < 128; ++k)
            acc = fmaf(st1[s][k], w2[k * 128 + c], acc);
        float d = (float)(s0 + s) * TSTEP;
        float Cf = 0.5f * (__cosf(d * 0.31415926535f) + 1.0f);
        T[(size_t)(s0 + s) * 128 + c] = acc * Cf;
    }
}

// ---------------------------------------------------------------------------
// counting sort by destination row
// ---------------------------------------------------------------------------
__global__ void hist_kernel(const int* __restrict__ eidx, int* __restrict__ cnt, int E)
{
    for (int e = blockIdx.x * 256 + threadIdx.x; e < E; e += gridDim.x * 256)
        atomicAdd(&cnt[eidx[e]], 1);
}

#define SCAN_CHUNK 1024
__global__ void scan_part(const int* __restrict__ cnt, int* __restrict__ part, int N)
{
    __shared__ int red[256];
    int b = blockIdx.x, tid = threadIdx.x;
    int base = b * SCAN_CHUNK + tid * 4;
    int s = 0;
#pragma unroll
    for (int i = 0; i < 4; ++i) { int idx = base + i; if (idx < N) s += cnt[idx]; }
    red[tid] = s;
    __syncthreads();
    for (int off = 128; off > 0; off >>= 1) {
        if (tid < off) red[tid] += red[tid + off];
        __syncthreads();
    }
    if (tid == 0) part[b] = red[0];
}

__global__ void scan_write(const int* __restrict__ cnt, const int* __restrict__ part,
                           int* __restrict__ cur, int N, int nblk)
{
    __shared__ int sc[256];
    int b = blockIdx.x, tid = threadIdx.x;
    int base = 0;
    for (int i = 0; i < b; ++i) base += part[i];
    int gbase = b * SCAN_CHUNK + tid * 4;
    int v[4];
#pragma unroll
    for (int i = 0; i < 4; ++i) { int idx = gbase + i; v[i] = (idx < N) ? cnt[idx] : 0; }
    int tsum = v[0] + v[1] + v[2] + v[3];
    sc[tid] = tsum;
    __syncthreads();
    for (int off = 1; off < 256; off <<= 1) {
        int add = (tid >= off) ? sc[tid - off] : 0;
        __syncthreads();
        sc[tid] += add;
        __syncthreads();
    }
    int tpre = base + sc[tid] - tsum;
    int run = 0;
#pragma unroll
    for (int i = 0; i < 4; ++i) {
        int idx = gbase + i;
        if (idx < N) cur[idx] = tpre + run;
        run += v[i];
    }
}

// scatter into sorted order; packed record {t, col} as int2 (one 8B store)
__global__ void scatter2(const int* __restrict__ eidx, const float* __restrict__ pos,
                         int* __restrict__ cur, int2* __restrict__ ec, int E)
{
    for (int e = blockIdx.x * 256 + threadIdx.x; e < E; e += gridDim.x * 256) {
        int r = eidx[e], c = eidx[E + e];
        float dx = pos[3 * r + 0] - pos[3 * c + 0];
        float dy = pos[3 * r + 1] - pos[3 * c + 1];
        float dz = pos[3 * r + 2] - pos[3 * c + 2];
        float d = sqrtf(dx * dx + dy * dy + dz * dz);
        int p = atomicAdd(&cur[r], 1);
        int2 v;
        v.x = __float_as_int(d * (TN / TMAXD));
        v.y = c;
        ec[p] = v;
    }
}

// ---------------------------------------------------------------------------
// node GEMM (fp32 accum): C = A @ Wg (+bias); OBF=1 -> write bf16
// ---------------------------------------------------------------------------
template<int OBF>
__global__ __launch_bounds__(256) void node_gemm(
    const float* __restrict__ A, const float* __restrict__ Wg,
    const float* __restrict__ bias, void* __restrict__ Cout, int nrows)
{
    __shared__ float sA[32][128];
    const int tid = threadIdx.x;
    const int tx = tid & 31;
    const int ty = tid >> 5;
    const int r0 = blockIdx.x * 32;

    for (int i = tid; i < 32 * 128; i += 256) {
        int r = i >> 7, k = i & 127;
        sA[r][k] = (r0 + r < nrows) ? A[(size_t)(r0 + r) * HID + k] : 0.f;
    }
    __syncthreads();

    f32x4 acc[4];
#pragma unroll
    for (int i = 0; i < 4; ++i) acc[i] = (f32x4){0.f, 0.f, 0.f, 0.f};

#pragma unroll 4
    for (int k = 0; k < 128; ++k) {
        f32x4 wv = *reinterpret_cast<const f32x4*>(Wg + k * HID + tx * 4);
        float a0 = sA[ty * 4 + 0][k];
        float a1 = sA[ty * 4 + 1][k];
        float a2 = sA[ty * 4 + 2][k];
        float a3 = sA[ty * 4 + 3][k];
        acc[0] += a0 * wv; acc[1] += a1 * wv; acc[2] += a2 * wv; acc[3] += a3 * wv;
    }

    f32x4 bv = (f32x4){0.f, 0.f, 0.f, 0.f};
    if (bias) bv = *reinterpret_cast<const f32x4*>(bias + tx * 4);
#pragma unroll
    for (int i = 0; i < 4; ++i) {
        int row = r0 + ty * 4 + i;
        if (row < nrows) {
            f32x4 o = acc[i] + bv;
            if (OBF) {
                u16* C = (u16*)Cout;
                ushort4 p;
                p.x = f2bf(o[0]); p.y = f2bf(o[1]); p.z = f2bf(o[2]); p.w = f2bf(o[3]);
                *reinterpret_cast<ushort4*>(C + (size_t)row * HID + tx * 4) = p;
            } else {
                float* C = (float*)Cout;
                *reinterpret_cast<f32x4*>(C + (size_t)row * HID + tx * 4) = o;
            }
        }
    }
}

// ---------------------------------------------------------------------------
// fused tail: out = ssp(agg @ lin2 + l2b) @ lin_w + lin_b
// intermediate t kept in LDS — saves a 25.6MB round-trip.
// ---------------------------------------------------------------------------
__global__ __launch_bounds__(256) void tail_gemm(
    const float* __restrict__ agg,
    const float* __restrict__ lin2, const float* __restrict__ l2b,
    const float* __restrict__ linw, const float* __restrict__ linb,
    float* __restrict__ out, int nrows)
{
    __shared__ float sA[32][128];
    __shared__ float sT[32][128];
    const int tid = threadIdx.x;
    const int tx = tid & 31;
    const int ty = tid >> 5;
    const int r0 = blockIdx.x * 32;

    for (int i = tid; i < 32 * 128; i += 256) {
        int r = i >> 7, k = i & 127;
        sA[r][k] = (r0 + r < nrows) ? agg[(size_t)(r0 + r) * HID + k] : 0.f;
    }
    __syncthreads();

    // GEMM1: t = ssp(agg @ lin2 + l2b) -> sT
    {
        f32x4 acc[4];
#pragma unroll
        for (int i = 0; i < 4; ++i) acc[i] = (f32x4){0.f, 0.f, 0.f, 0.f};
#pragma unroll 4
        for (int k = 0; k < 128; ++k) {
            f32x4 wv = *reinterpret_cast<const f32x4*>(lin2 + k * HID + tx * 4);
            float a0 = sA[ty * 4 + 0][k];
            float a1 = sA[ty * 4 + 1][k];
            float a2 = sA[ty * 4 + 2][k];
            float a3 = sA[ty * 4 + 3][k];
            acc[0] += a0 * wv; acc[1] += a1 * wv; acc[2] += a2 * wv; acc[3] += a3 * wv;
        }
        f32x4 bv = *reinterpret_cast<const f32x4*>(l2b + tx * 4);
#pragma unroll
        for (int i = 0; i < 4; ++i) {
            f32x4 o = acc[i] + bv;
            o[0] = sspf(o[0]); o[1] = sspf(o[1]); o[2] = sspf(o[2]); o[3] = sspf(o[3]);
            *reinterpret_cast<f32x4*>(&sT[ty * 4 + i][tx * 4]) = o;
        }
    }
    __syncthreads();

    // GEMM2: out = t @ lin_w + lin_b
    {
        f32x4 acc[4];
#pragma unroll
        for (int i = 0; i < 4; ++i) acc[i] = (f32x4){0.f, 0.f, 0.f, 0.f};
#pragma unroll 4
        for (int k = 0; k < 128; ++k) {
            f32x4 wv = *reinterpret_cast<const f32x4*>(linw + k * HID + tx * 4);
            float a0 = sT[ty * 4 + 0][k];
            float a1 = sT[ty * 4 + 1][k];
            float a2 = sT[ty * 4 + 2][k];
            float a3 = sT[ty * 4 + 3][k];
            acc[0] += a0 * wv; acc[1] += a1 * wv; acc[2] += a2 * wv; acc[3] += a3 * wv;
        }
        f32x4 bv = *reinterpret_cast<const f32x4*>(linb + tx * 4);
#pragma unroll
        for (int i = 0; i < 4; ++i) {
            int row = r0 + ty * 4 + i;
            if (row < nrows)
                *reinterpret_cast<f32x4*>(out + (size_t)row * HID + tx * 4) = acc[i] + bv;
        }
    }
}

// ---------------------------------------------------------------------------
// CSR message passing with table lerp, bf16 x-gather:
//   agg[r][c] = sum_{e in row r} lerp(T, t_e)[c] * x[col_e][c]
// ---------------------------------------------------------------------------
__global__ __launch_bounds__(256) void edge_csr(
    const int*  __restrict__ rowend,
    const int2* __restrict__ ec,      // packed {t_bits, col}, row-sorted
    const float* __restrict__ T,      // [TN][128]
    const u16*  __restrict__ bx,      // [N][128] bf16
    float*      __restrict__ agg,     // [N][128]
    int N)
{
    const int c    = threadIdx.x & 127;
    const int slot = threadIdx.x >> 7;
    const int r0   = blockIdx.x * RPB;
    const int rend = min(r0 + RPB, N);

    for (int r = r0 + slot; r < rend; r += 2) {
        int e = (r == 0) ? 0 : rowend[r - 1];
        const int ee = rowend[r];
        float acc = 0.f;

        for (; e + 3 < ee; e += 4) {
            int2 v0 = ec[e], v1 = ec[e + 1], v2 = ec[e + 2], v3 = ec[e + 3];
            float t0 = __int_as_float(v0.x), t1 = __int_as_float(v1.x);
            float t2 = __int_as_float(v2.x), t3 = __int_as_float(v3.x);
            int i0 = min((int)t0, TN - 2), i1 = min((int)t1, TN - 2);
            int i2 = min((int)t2, TN - 2), i3 = min((int)t3, TN - 2);
            float f0 = t0 - (float)i0, f1 = t1 - (float)i1;
            float f2 = t2 - (float)i2, f3 = t3 - (float)i3;
            const float* p0 = T + (size_t)i0 * HID + c;
            const float* p1 = T + (size_t)i1 * HID + c;
            const float* p2 = T + (size_t)i2 * HID + c;
            const float* p3 = T + (size_t)i3 * HID + c;
            float wa0 = p0[0], wb0 = p0[HID];
            float wa1 = p1[0], wb1 = p1[HID];
            float wa2 = p2[0], wb2 = p2[HID];
            float wa3 = p3[0], wb3 = p3[HID];
            float xv0 = bf2f(bx[(size_t)v0.y * HID + c]);
            float xv1 = bf2f(bx[(size_t)v1.y * HID + c]);
            float xv2 = bf2f(bx[(size_t)v2.y * HID + c]);
            float xv3 = bf2f(bx[(size_t)v3.y * HID + c]);
            acc = fmaf(fmaf(f0, wb0 - wa0, wa0), xv0, acc);
            acc = fmaf(fmaf(f1, wb1 - wa1, wa1), xv1, acc);
            acc = fmaf(fmaf(f2, wb2 - wa2, wa2), xv2, acc);
            acc = fmaf(fmaf(f3, wb3 - wa3, wa3), xv3, acc);
        }
        for (; e < ee; ++e) {
            int2 v0 = ec[e];
            float t0 = __int_as_float(v0.x);
            int   i0 = min((int)t0, TN - 2);
            float f0 = t0 - (float)i0;
            const float* p0 = T + (size_t)i0 * HID + c;
            float W0 = fmaf(f0, p0[HID] - p0[0], p0[0]);
            acc = fmaf(W0, bf2f(bx[(size_t)v0.y * HID + c]), acc);
        }
        agg[(size_t)r * HID + c] = acc;
    }
}

// ---------------------------------------------------------------------------
extern "C" void kernel_launch(void* const* d_in, const int* in_sizes, int n_in,
                              void* d_out, int out_size, void* d_ws, size_t ws_size,
                              hipStream_t stream)
{
    const float* h    = (const float*)d_in[0];
    const float* pos  = (const float*)d_in[1];
    const int*   eidx = (const int*)  d_in[2];
    const float* w1   = (const float*)d_in[3];
    const float* b1   = (const float*)d_in[4];
    const float* w2   = (const float*)d_in[5];
    const float* b2   = (const float*)d_in[6];
    const float* lin1 = (const float*)d_in[7];
    const float* lin2 = (const float*)d_in[8];
    const float* l2b  = (const float*)d_in[9];
    const float* linw = (const float*)d_in[10];
    const float* linb = (const float*)d_in[11];

    const int N = in_sizes[0] / HID;
    const int E = in_sizes[2] / 2;

    char* ws = (char*)d_ws;
    size_t off = 0;
    auto alloc = [&](size_t bytes) { char* p = ws + off; off = (off + bytes + 255) & ~(size_t)255; return p; };

    u16*   bx   = (u16*)  alloc((size_t)N * HID * sizeof(u16));   // x in bf16
    float* T    = (float*)alloc((size_t)TN * HID * sizeof(float));
    float* agg  = (float*)alloc((size_t)N * HID * sizeof(float));
    int*   cnt  = (int*)  alloc((size_t)N * sizeof(int));
    int*   cur  = (int*)  alloc((size_t)N * sizeof(int));
    int*   part = (int*)  alloc(256 * sizeof(int));
    int2*  ec   = (int2*) alloc((size_t)E * sizeof(int2));

    hipMemsetAsync(cnt, 0, (size_t)N * sizeof(int), stream);

    // Wc(d) lookup table (f32 exact MLP at 4096 sample distances)
    table_kernel<<<TN / TSPB, 256, 0, stream>>>(w1, b1, w2, b2, T);

    // counting sort of edges by destination row (cur -> CSR end offsets)
    hist_kernel<<<2048, 256, 0, stream>>>(eidx, cnt, E);
    const int nblk = (N + SCAN_CHUNK - 1) / SCAN_CHUNK;
    scan_part<<<nblk, 256, 0, stream>>>(cnt, part, N);
    scan_write<<<nblk, 256, 0, stream>>>(cnt, part, cur, N, nblk);
    scatter2<<<2048, 256, 0, stream>>>(eidx, pos, cur, ec, E);

    // x = h @ lin1  (bf16 output for the gather)
    node_gemm<1><<<(N + 31) / 32, 256, 0, stream>>>(h, lin1, nullptr, bx, N);

    // CSR gather-modulate-sum into agg, no atomics
    edge_csr<<<(N + RPB - 1) / RPB, 256, 0, stream>>>(cur, ec, T, bx, agg, N);

    // out = ssp(agg @ lin2 + l2b) @ lin_w + lin_b  (fused, t in LDS)
    tail_gemm<<<(N + 31) / 32, 256, 0, stream>>>(agg, lin2, l2b, linw, linb, (float*)d_out, N);
}

// Round 5
// 295.136 us; speedup vs baseline: 2.2697x; 1.0535x over previous
//
#include <hip/hip_runtime.h>
#include <hip/hip_bf16.h>
#include <math.h>

#define HID   128
#define NG    50
#define TN    4096          // table entries
#define TMAXD 16.0f         // table covers d in [0, 16)
#define RPB   8             // rows per block in CSR kernel (4 slots -> 2 rows/thread)
#define TSPB  16            // samples per block in table branch
#define HB    1024          // hist blocks in fused0

typedef __attribute__((ext_vector_type(4))) float f32x4;
typedef unsigned short u16;
typedef unsigned int   u32;

#define LOG2F 0.69314718056f

__device__ __forceinline__ float sspf(float v) {
    if (v > 15.f) return v - LOG2F;
    return __logf(1.f + __expf(v)) - LOG2F;
}

__device__ __forceinline__ u16 f2bf(float f) {
    __hip_bfloat16 h = __float2bfloat16(f);
    return *reinterpret_cast<u16*>(&h);
}
__device__ __forceinline__ float bf2f(u32 v) {
    union { u32 u; float f; } x; x.u = v << 16; return x.f;
}

// ---------------------------------------------------------------------------
// fused0: three INDEPENDENT stages partitioned by blockIdx:
//   [0, 256)            : Wc(d) lookup table -> Tp (pair-interleaved)
//   [256, 256+ngb)      : bx = bf16(h @ lin1)
//   [256+ngb, +HB)      : hist of destination rows
// ---------------------------------------------------------------------------
union SMem {
    struct { float sattr[TSPB + 1][64]; float st1[TSPB + 1][128]; float sW[TSPB + 1][128]; } tb;
    float sA[32][128];
};

__global__ __launch_bounds__(256) void fused0(
    const float* __restrict__ w1, const float* __restrict__ b1,
    const float* __restrict__ w2, const float* __restrict__ b2,
    float2* __restrict__ Tp,
    const float* __restrict__ h, const float* __restrict__ lin1, u16* __restrict__ bx,
    const int* __restrict__ eidx, int* __restrict__ cnt,
    int N, int E)
{
    __shared__ SMem sm;
    const int tid = threadIdx.x;
    const int b   = blockIdx.x;
    const int ngb = (N + 31) / 32;

    if (b < 256) {
        // ---- table: 17 samples (overlap 1 for the pair) --------------------
        const int s0 = b * TSPB;
        const float TSTEP = TMAXD / TN;
        const float GSTEP = 10.0f / 49.0f;
        const float COEFF = -0.5f / (GSTEP * GSTEP);

        for (int idx = tid; idx < (TSPB + 1) * 64; idx += 256) {
            int s = idx >> 6, g = idx & 63;
            float v = 0.f;
            if (g < NG) {
                float d = (float)(s0 + s) * TSTEP;
                float t = d - (float)g * GSTEP;
                v = __expf(COEFF * t * t);
            }
            sm.tb.sattr[s][g] = v;
        }
        __syncthreads();

        const int c  = tid & 127;
        const int sh = tid >> 7;

        for (int s = sh; s < TSPB + 1; s += 2) {
            float acc = b1[c];
#pragma unroll
            for (int g = 0; g < NG; ++g)
                acc = fmaf(sm.tb.sattr[s][g], w1[g * 128 + c], acc);
            sm.tb.st1[s][c] = sspf(acc);
        }
        __syncthreads();

        for (int s = sh; s < TSPB + 1; s += 2) {
            float acc = b2[c];
#pragma unroll 8
            for (int k = 0; k < 128; ++k)
                acc = fmaf(sm.tb.st1[s][k], w2[k * 128 + c], acc);
            float d = (float)(s0 + s) * TSTEP;
            float Cf = 0.5f * (__cosf(d * 0.31415926535f) + 1.0f);
            sm.tb.sW[s][c] = acc * Cf;
        }
        __syncthreads();

        for (int j = sh; j < TSPB; j += 2) {
            float2 p; p.x = sm.tb.sW[j][c]; p.y = sm.tb.sW[j + 1][c];
            Tp[(size_t)(s0 + j) * HID + c] = p;
        }
    } else if (b < 256 + ngb) {
        // ---- node GEMM: bx = bf16(h @ lin1) --------------------------------
        const int nb = b - 256;
        const int tx = tid & 31;
        const int ty = tid >> 5;
        const int r0 = nb * 32;

        for (int i = tid; i < 32 * 128; i += 256) {
            int r = i >> 7, k = i & 127;
            sm.sA[r][k] = (r0 + r < N) ? h[(size_t)(r0 + r) * HID + k] : 0.f;
        }
        __syncthreads();

        f32x4 acc[4];
#pragma unroll
        for (int i = 0; i < 4; ++i) acc[i] = (f32x4){0.f, 0.f, 0.f, 0.f};

#pragma unroll 4
        for (int k = 0; k < 128; ++k) {
            f32x4 wv = *reinterpret_cast<const f32x4*>(lin1 + k * HID + tx * 4);
            float a0 = sm.sA[ty * 4 + 0][k];
            float a1 = sm.sA[ty * 4 + 1][k];
            float a2 = sm.sA[ty * 4 + 2][k];
            float a3 = sm.sA[ty * 4 + 3][k];
            acc[0] += a0 * wv; acc[1] += a1 * wv; acc[2] += a2 * wv; acc[3] += a3 * wv;
        }
#pragma unroll
        for (int i = 0; i < 4; ++i) {
            int row = r0 + ty * 4 + i;
            if (row < N) {
                ushort4 p;
                p.x = f2bf(acc[i][0]); p.y = f2bf(acc[i][1]);
                p.z = f2bf(acc[i][2]); p.w = f2bf(acc[i][3]);
                *reinterpret_cast<ushort4*>(bx + (size_t)row * HID + tx * 4) = p;
            }
        }
    } else {
        // ---- hist ----------------------------------------------------------
        const int hb = b - 256 - ngb;
        for (int e = hb * 256 + tid; e < E; e += HB * 256)
            atomicAdd(&cnt[eidx[e]], 1);
    }
}

// ---------------------------------------------------------------------------
// single-block exclusive scan of cnt -> cur (chunked Hillis-Steele, 1024 thr)
// ---------------------------------------------------------------------------
__global__ __launch_bounds__(1024) void scan_kernel(
    const int* __restrict__ cnt, int* __restrict__ cur, int N)
{
    __shared__ int sc[1024];
    const int tid = threadIdx.x;
    int base = 0;

    for (int start = 0; start < N; start += 4096) {
        int gbase = start + tid * 4;
        int v[4];
#pragma unroll
        for (int i = 0; i < 4; ++i) { int idx = gbase + i; v[i] = (idx < N) ? cnt[idx] : 0; }
        int tsum = v[0] + v[1] + v[2] + v[3];
        sc[tid] = tsum;
        __syncthreads();
        for (int off = 1; off < 1024; off <<= 1) {
            int add = (tid >= off) ? sc[tid - off] : 0;
            __syncthreads();
            sc[tid] += add;
            __syncthreads();
        }
        int tpre = base + sc[tid] - tsum;
        int run = 0;
#pragma unroll
        for (int i = 0; i < 4; ++i) {
            int idx = gbase + i;
            if (idx < N) cur[idx] = tpre + run;
            run += v[i];
        }
        int tot = sc[1023];
        __syncthreads();
        base += tot;
    }
}

// scatter into sorted order; packed record {t_bits, col} as int2
__global__ void scatter2(const int* __restrict__ eidx, const float* __restrict__ pos,
                         int* __restrict__ cur, int2* __restrict__ ec, int E)
{
    for (int e = blockIdx.x * 256 + threadIdx.x; e < E; e += gridDim.x * 256) {
        int r = eidx[e], c = eidx[E + e];
        float dx = pos[3 * r + 0] - pos[3 * c + 0];
        float dy = pos[3 * r + 1] - pos[3 * c + 1];
        float dz = pos[3 * r + 2] - pos[3 * c + 2];
        float d = sqrtf(dx * dx + dy * dy + dz * dz);
        int p = atomicAdd(&cur[r], 1);
        int2 v;
        v.x = __float_as_int(d * (TN / TMAXD));
        v.y = c;
        ec[p] = v;
    }
}

// ---------------------------------------------------------------------------
// CSR message passing, one WAVE per row, 2 columns/lane (float2):
//   agg[r][c] = sum_{e in row r} lerp(Tp, t_e)[c] * bx[col_e][c]
// Tp[i][c] = (W[i][c], W[i+1][c])  ->  one float4 load gives both lerp
// endpoints for both columns.
// ---------------------------------------------------------------------------
__global__ __launch_bounds__(256) void edge_csr(
    const int*    __restrict__ rowend,
    const int2*   __restrict__ ec,
    const float2* __restrict__ Tp,     // [TN][128] pairs
    const u16*    __restrict__ bx,     // [N][128] bf16
    float*        __restrict__ agg,    // [N][128]
    int N)
{
    const int lane = threadIdx.x & 63;
    const int slot = threadIdx.x >> 6;          // 0..3 row slots
    const int c2   = lane * 2;                  // columns c2, c2+1
    const int r0   = blockIdx.x * RPB;
    const int rend = min(r0 + RPB, N);
    const float* Tf = (const float*)Tp;

    for (int r = r0 + slot; r < rend; r += 4) {
        int e = (r == 0) ? 0 : rowend[r - 1];
        const int ee = rowend[r];
        float ax = 0.f, ay = 0.f;

        for (; e + 3 < ee; e += 4) {
            int2 v0 = ec[e], v1 = ec[e + 1], v2 = ec[e + 2], v3 = ec[e + 3];
            float t0 = __int_as_float(v0.x), t1 = __int_as_float(v1.x);
            float t2 = __int_as_float(v2.x), t3 = __int_as_float(v3.x);
            int i0 = min((int)t0, TN - 2), i1 = min((int)t1, TN - 2);
            int i2 = min((int)t2, TN - 2), i3 = min((int)t3, TN - 2);
            float f0 = t0 - (float)i0, f1 = t1 - (float)i1;
            float f2 = t2 - (float)i2, f3 = t3 - (float)i3;
            f32x4 T0 = *reinterpret_cast<const f32x4*>(Tf + ((size_t)i0 * HID + c2) * 2);
            f32x4 T1 = *reinterpret_cast<const f32x4*>(Tf + ((size_t)i1 * HID + c2) * 2);
            f32x4 T2 = *reinterpret_cast<const f32x4*>(Tf + ((size_t)i2 * HID + c2) * 2);
            f32x4 T3 = *reinterpret_cast<const f32x4*>(Tf + ((size_t)i3 * HID + c2) * 2);
            u32 X0 = *reinterpret_cast<const u32*>(bx + (size_t)v0.y * HID + c2);
            u32 X1 = *reinterpret_cast<const u32*>(bx + (size_t)v1.y * HID + c2);
            u32 X2 = *reinterpret_cast<const u32*>(bx + (size_t)v2.y * HID + c2);
            u32 X3 = *reinterpret_cast<const u32*>(bx + (size_t)v3.y * HID + c2);

            ax = fmaf(fmaf(f0, T0[1] - T0[0], T0[0]), bf2f(X0 & 0xffffu), ax);
            ay = fmaf(fmaf(f0, T0[3] - T0[2], T0[2]), bf2f(X0 >> 16), ay);
            ax = fmaf(fmaf(f1, T1[1] - T1[0], T1[0]), bf2f(X1 & 0xffffu), ax);
            ay = fmaf(fmaf(f1, T1[3] - T1[2], T1[2]), bf2f(X1 >> 16), ay);
            ax = fmaf(fmaf(f2, T2[1] - T2[0], T2[0]), bf2f(X2 & 0xffffu), ax);
            ay = fmaf(fmaf(f2, T2[3] - T2[2], T2[2]), bf2f(X2 >> 16), ay);
            ax = fmaf(fmaf(f3, T3[1] - T3[0], T3[0]), bf2f(X3 & 0xffffu), ax);
            ay = fmaf(fmaf(f3, T3[3] - T3[2], T3[2]), bf2f(X3 >> 16), ay);
        }
        for (; e < ee; ++e) {
            int2 v0 = ec[e];
            float t0 = __int_as_float(v0.x);
            int   i0 = min((int)t0, TN - 2);
            float f0 = t0 - (float)i0;
            f32x4 T0 = *reinterpret_cast<const f32x4*>(Tf + ((size_t)i0 * HID + c2) * 2);
            u32 X0 = *reinterpret_cast<const u32*>(bx + (size_t)v0.y * HID + c2);
            ax = fmaf(fmaf(f0, T0[1] - T0[0], T0[0]), bf2f(X0 & 0xffffu), ax);
            ay = fmaf(fmaf(f0, T0[3] - T0[2], T0[2]), bf2f(X0 >> 16), ay);
        }
        float2 o; o.x = ax; o.y = ay;
        *reinterpret_cast<float2*>(agg + (size_t)r * HID + c2) = o;
    }
}

// ---------------------------------------------------------------------------
// fused tail: out = ssp(agg @ lin2 + l2b) @ lin_w + lin_b   (t in LDS)
// ---------------------------------------------------------------------------
__global__ __launch_bounds__(256) void tail_gemm(
    const float* __restrict__ agg,
    const float* __restrict__ lin2, const float* __restrict__ l2b,
    const float* __restrict__ linw, const float* __restrict__ linb,
    float* __restrict__ out, int nrows)
{
    __shared__ float sA[32][128];
    __shared__ float sT[32][128];
    const int tid = threadIdx.x;
    const int tx = tid & 31;
    const int ty = tid >> 5;
    const int r0 = blockIdx.x * 32;

    for (int i = tid; i < 32 * 128; i += 256) {
        int r = i >> 7, k = i & 127;
        sA[r][k] = (r0 + r < nrows) ? agg[(size_t)(r0 + r) * HID + k] : 0.f;
    }
    __syncthreads();

    {
        f32x4 acc[4];
#pragma unroll
        for (int i = 0; i < 4; ++i) acc[i] = (f32x4){0.f, 0.f, 0.f, 0.f};
#pragma unroll 4
        for (int k = 0; k < 128; ++k) {
            f32x4 wv = *reinterpret_cast<const f32x4*>(lin2 + k * HID + tx * 4);
            float a0 = sA[ty * 4 + 0][k];
            float a1 = sA[ty * 4 + 1][k];
            float a2 = sA[ty * 4 + 2][k];
            float a3 = sA[ty * 4 + 3][k];
            acc[0] += a0 * wv; acc[1] += a1 * wv; acc[2] += a2 * wv; acc[3] += a3 * wv;
        }
        f32x4 bv = *reinterpret_cast<const f32x4*>(l2b + tx * 4);
#pragma unroll
        for (int i = 0; i < 4; ++i) {
            f32x4 o = acc[i] + bv;
            o[0] = sspf(o[0]); o[1] = sspf(o[1]); o[2] = sspf(o[2]); o[3] = sspf(o[3]);
            *reinterpret_cast<f32x4*>(&sT[ty * 4 + i][tx * 4]) = o;
        }
    }
    __syncthreads();

    {
        f32x4 acc[4];
#pragma unroll
        for (int i = 0; i < 4; ++i) acc[i] = (f32x4){0.f, 0.f, 0.f, 0.f};
#pragma unroll 4
        for (int k = 0; k < 128; ++k) {
            f32x4 wv = *reinterpret_cast<const f32x4*>(linw + k * HID + tx * 4);
            float a0 = sT[ty * 4 + 0][k];
            float a1 = sT[ty * 4 + 1][k];
            float a2 = sT[ty * 4 + 2][k];
            float a3 = sT[ty * 4 + 3][k];
            acc[0] += a0 * wv; acc[1] += a1 * wv; acc[2] += a2 * wv; acc[3] += a3 * wv;
        }
        f32x4 bv = *reinterpret_cast<const f32x4*>(linb + tx * 4);
#pragma unroll
        for (int i = 0; i < 4; ++i) {
            int row = r0 + ty * 4 + i;
            if (row < nrows)
                *reinterpret_cast<f32x4*>(out + (size_t)row * HID + tx * 4) = acc[i] + bv;
        }
    }
}

// ---------------------------------------------------------------------------
extern "C" void kernel_launch(void* const* d_in, const int* in_sizes, int n_in,
                              void* d_out, int out_size, void* d_ws, size_t ws_size,
                              hipStream_t stream)
{
    const float* h    = (const float*)d_in[0];
    const float* pos  = (const float*)d_in[1];
    const int*   eidx = (const int*)  d_in[2];
    const float* w1   = (const float*)d_in[3];
    const float* b1   = (const float*)d_in[4];
    const float* w2   = (const float*)d_in[5];
    const float* b2   = (const float*)d_in[6];
    const float* lin1 = (const float*)d_in[7];
    const float* lin2 = (const float*)d_in[8];
    const float* l2b  = (const float*)d_in[9];
    const float* linw = (const float*)d_in[10];
    const float* linb = (const float*)d_in[11];

    const int N = in_sizes[0] / HID;
    const int E = in_sizes[2] / 2;

    char* ws = (char*)d_ws;
    size_t off = 0;
    auto alloc = [&](size_t bytes) { char* p = ws + off; off = (off + bytes + 255) & ~(size_t)255; return p; };

    u16*    bx  = (u16*)   alloc((size_t)N * HID * sizeof(u16));
    float2* Tp  = (float2*)alloc((size_t)TN * HID * sizeof(float2));
    float*  agg = (float*) alloc((size_t)N * HID * sizeof(float));
    int*    cnt = (int*)   alloc((size_t)N * sizeof(int));
    int*    cur = (int*)   alloc((size_t)N * sizeof(int));
    int2*   ec  = (int2*)  alloc((size_t)E * sizeof(int2));

    hipMemsetAsync(cnt, 0, (size_t)N * sizeof(int), stream);

    // table + x=h@lin1 (bf16) + hist, one partitioned launch
    const int ngb = (N + 31) / 32;
    fused0<<<256 + ngb + HB, 256, 0, stream>>>(w1, b1, w2, b2, Tp,
                                               h, lin1, bx, eidx, cnt, N, E);

    // exclusive scan cnt -> cur (single block)
    scan_kernel<<<1, 1024, 0, stream>>>(cnt, cur, N);

    // scatter edges into row-sorted order (+ distance -> table coord)
    scatter2<<<1024, 256, 0, stream>>>(eidx, pos, cur, ec, E);

    // CSR gather-modulate-sum into agg, one wave/row, no atomics
    edge_csr<<<(N + RPB - 1) / RPB, 256, 0, stream>>>(cur, ec, Tp, bx, agg, N);

    // out = ssp(agg @ lin2 + l2b) @ lin_w + lin_b
    tail_gemm<<<(N + 31) / 32, 256, 0, stream>>>(agg, lin2, l2b, linw, linb, (float*)d_out, N);
}